// Round 13
// baseline (4798.560 us; speedup 1.0000x reference)
//
#include <hip/hip_runtime.h>

// PopulationODE: sequential RK4 scan, T=4096, state=4, HID=32.
// Round-13: 16 waves (1024 thr), TWO steps per iteration, 1 barrier/iter.
//   grp0: correct step 2j   (exact y,zb; stage inputs P(2j))
//   grp1: correct step 2j+1 (y guessed from P(2j)-combine, err ~1e-9)
//   grp2: predict step 2j+2 (inputs P(2j+1), 1 step stale — r12 pattern)
//   grp3: predict step 2j+3 (inputs P(2j+1), 2 steps stale)
// Exchange: per wave only 5 scalars {K0..K3,gk} (Ka/Kb are 2-valued per
// lane, gk uniform) -> lane0 writes b128+b32 to SC[2][16][8]; readers use
// broadcast-friendly b64(+mhi offset)+b32. Kills r12's per-lane LDS burst.
// Numerics: r8/r11/r12 lineage (2-sweep Jacobi per step, absmax 0.0).

__device__ __forceinline__ float fexp2(float x) { return __builtin_amdgcn_exp2f(x); }
__device__ __forceinline__ float frcp(float x) { return __builtin_amdgcn_rcpf(x); }
#define C_TANH 2.8853900817779268f
#define C_NSIG (-1.4426950408889634f)

template<int CTRL>
__device__ __forceinline__ float dppmov(float x) {
  return __int_as_float(__builtin_amdgcn_update_dpp(
      0, __float_as_int(x), CTRL, 0xF, 0xF, true));
}
#define RORc(K) (0x120 | (K))

__device__ __forceinline__ void p16swap(float& a, float& b) {
  asm("s_nop 1\n\tv_permlane16_swap_b32 %0, %1" : "+v"(a), "+v"(b));
}
__device__ __forceinline__ void p32swap(float& a, float& b) {
  asm("s_nop 1\n\tv_permlane32_swap_b32 %0, %1" : "+v"(a), "+v"(b));
}

#define MV8(W, BZ, X, SOUT) do {                                       \
    float b0_ = fmaf((X),             W[0], (BZ));                     \
    float b1_ = dppmov<RORc(1)>(X)  * W[1];                            \
    float b2_ = dppmov<RORc(2)>(X)  * W[2];                            \
    float b3_ = dppmov<RORc(3)>(X)  * W[3];                            \
    float b4_ = dppmov<RORc(4)>(X)  * W[4];                            \
    float b5_ = dppmov<RORc(5)>(X)  * W[5];                            \
    float b6_ = dppmov<RORc(6)>(X)  * W[6];                            \
    float b7_ = dppmov<RORc(7)>(X)  * W[7];                            \
    b0_ = fmaf(dppmov<RORc(8)>(X),  W[8],  b0_);                       \
    b1_ = fmaf(dppmov<RORc(9)>(X),  W[9],  b1_);                       \
    b2_ = fmaf(dppmov<RORc(10)>(X), W[10], b2_);                       \
    b3_ = fmaf(dppmov<RORc(11)>(X), W[11], b3_);                       \
    b4_ = fmaf(dppmov<RORc(12)>(X), W[12], b4_);                       \
    b5_ = fmaf(dppmov<RORc(13)>(X), W[13], b5_);                       \
    b6_ = fmaf(dppmov<RORc(14)>(X), W[14], b6_);                       \
    b7_ = fmaf(dppmov<RORc(15)>(X), W[15], b7_);                       \
    SOUT = ((b0_ + b1_) + (b2_ + b3_)) + ((b4_ + b5_) + (b6_ + b7_));  \
  } while (0)

__global__ __launch_bounds__(1024, 1) __attribute__((amdgpu_waves_per_eu(4, 4)))
void ode_kernel(const float* __restrict__ s_grid,
                const float* __restrict__ y0in,
                const float* __restrict__ Win,
                const float* __restrict__ bin_,
                const float* __restrict__ W1a, const float* __restrict__ b1a,
                const float* __restrict__ W1b, const float* __restrict__ b1b,
                const float* __restrict__ W2a, const float* __restrict__ b2a,
                const float* __restrict__ W2b, const float* __restrict__ b2b,
                const float* __restrict__ Wout, const float* __restrict__ bout,
                const float* __restrict__ Aarr,
                float* __restrict__ out, int T) {
  const int tid = threadIdx.x;
  const int wv = tid >> 6;        // 0..15
  const int grp = wv >> 2;        // 0..3 (see header)
  const int st = wv & 3;          // RK stage owned
  const int lane = tid & 63;
  const int i = lane & 15;
  const int m = lane >> 4;
  const int mlo = m & 1;
  const int mhi = m >> 1;

  // ---- LDS ----
  __shared__ float s_lds[4096];
  __shared__ float SC[2][16][8];  // [buf][slot]{K0,K1,K2,K3,gk,pad...}
  for (int idx = tid; idx < T && idx < 4096; idx += 1024)
    s_lds[idx] = s_grid[idx];
  __syncthreads();

  // ---- direction probes ----
  int delta;
  {
    float pr = (float)i;
    float pr1 = dppmov<RORc(1)>(pr);
    delta = (((int)pr1) - i) & 15;
  }
  bool p32_c_low;
  {
    float v = (float)(lane >> 5);
    float c = v, d = v;
    p32swap(c, d);
    p32_c_low = (c == 0.0f);
  }

  // ---- weight prep (identical to r7-r12) ----
  const int rA = 16 * mhi + i, hA = mlo;
  const int rB = 16 * mlo + i, hB = mhi;
  const int r_in = 16 * mlo + i;
  const int e1 = r_in;

  float w1a[16], w2a[16], m21[16];
#pragma unroll 1
  for (int k = 0; k < 16; ++k) {
    int cA = hA * 16 + ((i + delta * k) & 15);
    int cB = hB * 16 + ((i + delta * k) & 15);
    w1a[k] = W1a[rA * 32 + cA] * (-2.0f * C_TANH);
    w2a[k] = W2a[rA * 32 + cA] * (-2.0f * C_TANH);
    float acc = 0.0f;
    for (int q = 0; q < 32; ++q)
      acc = fmaf(W2a[rB * 32 + q], W1b[q * 32 + cB], acc);
    m21[k] = acc * (-2.0f * C_TANH);
  }
  float bz1a;
  {
    float rs = 0.0f;
    for (int c = 0; c < 32; ++c) rs += W1a[rA * 32 + c];
    bz1a = hA ? 0.0f : C_TANH * (b1a[rA] + rs);
  }
  float c2sel;
  {
    float rs2a = 0.0f, m21rs = 0.0f, wb = 0.0f;
    for (int q = 0; q < 32; ++q) {
      float w2q = W2a[rB * 32 + q];
      rs2a += w2q;
      float rs1bq = 0.0f;
      for (int c = 0; c < 32; ++c) rs1bq += W1b[q * 32 + c];
      m21rs = fmaf(w2q, rs1bq, m21rs);
      wb = fmaf(w2q, b1b[q], wb);
    }
    c2sel = hB ? 0.0f : C_TANH * (rs2a + m21rs + wb + b2a[rB]);
  }
  const bool seedsel = (mlo == mhi);

  float winy0 = Win[r_in * 5 + 0] * C_TANH;
  float winy1 = Win[r_in * 5 + 1] * C_TANH;
  float winy2 = Win[r_in * 5 + 2] * C_TANH;
  float winy3 = Win[r_in * 5 + 3] * C_TANH;
  float wins  = Win[r_in * 5 + 4] * C_TANH;
  float binr  = bin_[r_in] * C_TANH;
  float gsel_a = mhi ? winy2 : winy0;
  float gsel_b = mhi ? winy3 : winy1;

  const int ra_ = 2 * mhi, rb_ = 2 * mhi + 1;
  float woXa = Wout[ra_ * 32 + e1] * (-2.0f * C_NSIG);
  float woXb = Wout[rb_ * 32 + e1] * (-2.0f * C_NSIG);
  float wo1a, wo1b, wo2a, wo2b, boa, bob;
  {
    float w1s_a = 0.0f, w1s_b = 0.0f, w2s_a = 0.0f, w2s_b = 0.0f;
    float rsX_a = 0.0f, rsX_b = 0.0f, rs1_a = 0.0f, rs1_b = 0.0f;
    float rs2_a = 0.0f, rs2_b = 0.0f, bt_a = 0.0f, bt_b = 0.0f;
    for (int q = 0; q < 32; ++q) {
      float waq = Wout[ra_ * 32 + q], wbq = Wout[rb_ * 32 + q];
      w1s_a = fmaf(waq, W1b[q * 32 + e1], w1s_a);
      w1s_b = fmaf(wbq, W1b[q * 32 + e1], w1s_b);
      w2s_a = fmaf(waq, W2b[q * 32 + e1], w2s_a);
      w2s_b = fmaf(wbq, W2b[q * 32 + e1], w2s_b);
      rsX_a += waq; rsX_b += wbq;
      float rs1bq = 0.0f, rs2bq = 0.0f;
      for (int c = 0; c < 32; ++c) {
        rs1bq += W1b[q * 32 + c];
        rs2bq += W2b[q * 32 + c];
      }
      rs1_a = fmaf(waq, rs1bq, rs1_a); rs1_b = fmaf(wbq, rs1bq, rs1_b);
      rs2_a = fmaf(waq, rs2bq, rs2_a); rs2_b = fmaf(wbq, rs2bq, rs2_b);
      float bs = b1b[q] + b2b[q];
      bt_a = fmaf(waq, bs, bt_a); bt_b = fmaf(wbq, bs, bt_b);
    }
    wo1a = w1s_a * (-2.0f * C_NSIG); wo1b = w1s_b * (-2.0f * C_NSIG);
    wo2a = w2s_a * (-2.0f * C_NSIG); wo2b = w2s_b * (-2.0f * C_NSIG);
    boa = (bout[ra_] + bt_a + rsX_a + rs1_a + rs2_a) * (C_NSIG / 32.0f);
    bob = (bout[rb_] + bt_b + rsX_b + rs1_b + rs2_b) * (C_NSIG / 32.0f);
  }
  float Aa = mhi ? Aarr[2] : Aarr[0];
  float Ab = mhi ? Aarr[3] : Aarr[1];

  auto relayout = [&](float v) -> float {
    float c = v, d = v;
    p32swap(c, d);
    float lo = p32_c_low ? c : d;
    float hi = p32_c_low ? d : c;
    return mlo ? hi : lo;
  };

  float pfa, pfb, wpa, wpb, na, nb, gkv;

  auto setpref = [&](float yA, float yB) {
    float sa = frcp(1.0f + fexp2(yA * C_NSIG));
    float sb = frcp(1.0f + fexp2(yB * C_NSIG));
    pfa = 0.01f * sa * (Aa - sa);
    pfb = 0.01f * sb * (Ab - sb);
    wpa = gsel_a * pfa;
    wpb = gsel_b * pfb;
  };

  auto STAGE = [&](float zin) {
    float g0v = frcp(fexp2(zin) + 1.0f);                   // ABAB
    float u1; MV8(w1a, bz1a, g0v, u1);
    { float b = u1; p16swap(u1, b); u1 += b; }             // AABB
    float q2; MV8(w2a, 0.0f, g0v, q2);
    { float b = q2; p16swap(q2, b); q2 += b; }             // AABB
    float g1 = frcp(fexp2(u1) + 1.0f);
    float g1r = relayout(g1);
    float seed = (seedsel ? q2 : 0.0f) + c2sel;
    float u2; MV8(m21, seed, g1, u2);
    { float b = u2; p32swap(u2, b); u2 += b; }             // ABAB
    float g2 = frcp(fexp2(u2) + 1.0f);
    float ph0 = fmaf(wo1a, g1r, fmaf(woXa, g0v, boa));
    float ph1 = fmaf(wo1b, g1r, fmaf(woXb, g0v, bob));
    float p0 = fmaf(wo2a, g2, ph0);
    float p1 = fmaf(wo2b, g2, ph1);
    p0 += dppmov<RORc(8)>(p0); p1 += dppmov<RORc(8)>(p1);
    p0 += dppmov<RORc(4)>(p0); p1 += dppmov<RORc(4)>(p1);
    p0 += dppmov<RORc(2)>(p0); p1 += dppmov<RORc(2)>(p1);
    p0 += dppmov<RORc(1)>(p0); p1 += dppmov<RORc(1)>(p1);
    { float q = p0; p16swap(p0, q); p0 += q; }
    { float q = p1; p16swap(p1, q); p1 += q; }
    na = frcp(1.0f + fexp2(p0));
    nb = frcp(1.0f + fexp2(p1));
    float gp = fmaf(wpb, nb, wpa * na);
    float gq = gp;
    p32swap(gp, gq);
    gkv = gp + gq;
  };

  // scalar exchange read: own-component Ka/Kb via mhi-offset b64, gk b32
  auto rdslot = [&](int pp, int ss, float& gk, float& ka, float& kb) {
    float2 kk = *reinterpret_cast<float2*>(&SC[pp][ss][mhi << 1]);
    ka = kk.x; kb = kk.y;
    gk = SC[pp][ss][4];
  };
  // combine 4 consecutive slots with RK weights {1,2,2,1}
  auto rd4 = [&](int pp, int s0_, float& ag, float& aa, float& ab) {
    float g, a, b;
    rdslot(pp, s0_ + 0, g, a, b); ag = g; aa = a; ab = b;
    rdslot(pp, s0_ + 1, g, a, b);
    ag = fmaf(2.0f, g, ag); aa = fmaf(2.0f, a, aa); ab = fmaf(2.0f, b, ab);
    rdslot(pp, s0_ + 2, g, a, b);
    ag = fmaf(2.0f, g, ag); aa = fmaf(2.0f, a, aa); ab = fmaf(2.0f, b, ab);
    rdslot(pp, s0_ + 3, g, a, b); ag += g; aa += a; ab += b;
  };
  // write this wave's 5 scalars (lane 0)
  auto wrslot = [&](int qq, float Ka, float Kb) {
    float c0 = Ka, d0 = Ka; p32swap(c0, d0);
    float hiKa = p32_c_low ? d0 : c0;
    float c1 = Kb, d1 = Kb; p32swap(c1, d1);
    float hiKb = p32_c_low ? d1 : c1;
    if (lane == 0) {
      *reinterpret_cast<float4*>(&SC[qq][wv][0]) =
          make_float4(Ka, Kb, hiKa, hiKb);   // K0,K1,K2,K3
      SC[qq][wv][4] = gkv;
    }
  };

  // ---- state (every wave tracks identically) ----
  float y00 = y0in[0], y01 = y0in[1], y02 = y0in[2], y03 = y0in[3];
  float ya = mhi ? y02 : y00;
  float yb = mhi ? y03 : y01;

  if (wv == 0 && (lane & 0x1E) == 0)
    out[(lane >> 4) + (lane & 1)] = (lane & 1) ? yb : ya;

  // s window: s0..s4 = s[2j .. 2j+4] (clamped)
  auto sat = [&](int idx) { return s_lds[idx < T ? idx : (T - 1)]; };
  float s0 = s_lds[0], s1 = sat(1), s2 = sat(2), s3 = sat(3), s4 = sat(4);

  float zb_e = fmaf(winy0, y00, fmaf(winy1, y01, fmaf(winy2, y02,
               fmaf(winy3, y03, fmaf(wins, s0, binr)))));

  // ---- prologue: grp2 predicts step 0, grp3 predicts step 1 ----
  if (grp >= 2) {
    float h0 = s1 - s0;
    float zB = (grp == 2) ? zb_e : fmaf(wins, h0, zb_e);
    setpref(ya, yb);
    STAGE(zB);                       // zero stage-input guesses (r8 iter1)
    wrslot(0, pfa * na, pfb * nb);   // slots 8..15 of buf 0
  }
  __syncthreads();

  float h6p0 = 0.0f, h6p1 = 0.0f, hsumP = 0.0f;

  const int NJ = T >> 1;   // pairs of steps; steps 2j,2j+1
  for (int j = 0; j < NJ; ++j) {
    const int p = j & 1, q = p ^ 1;
    float h0 = s1 - s0, h1 = s2 - s1, h2 = s3 - s2, h3 = s4 - s3;
    float h6_0 = h0 * (1.0f / 6.0f);
    float h6_1 = h1 * (1.0f / 6.0f);
    float h6_2 = h2 * (1.0f / 6.0f);

    // ---- reads ----
    float agC0, aaC0, abC0, agC1, aaC1, abC1;
    if (j) {
      rd4(p, 0, agC0, aaC0, abC0);   // C(2j-2)
      rd4(p, 4, agC1, aaC1, abC1);   // C(2j-1)
    }
    float agP0 = 0, aaP0 = 0, abP0 = 0, agP1 = 0, aaP1 = 0, abP1 = 0;
    if (grp >= 1) rd4(p, 8, agP0, aaP0, abP0);    // P(2j) combine
    if (grp >= 2) rd4(p, 12, agP1, aaP1, abP1);   // P(2j+1) combine
    const int sl_in = ((grp == 0) ? 8 : 12) + (st ? st - 1 : 0);
    float gin, kain, kbin;
    rdslot(p, sl_in, gin, kain, kbin);

    // ---- finalize exact state from corrections (j>0) ----
    if (j) {
      float yam = fmaf(h6p0, aaC0, ya);   // y(2j-1)
      float ybm = fmaf(h6p0, abC0, yb);
      ya = fmaf(h6p1, aaC1, yam);         // y(2j)
      yb = fmaf(h6p1, abC1, ybm);
      zb_e = fmaf(h6p1, agC1, fmaf(h6p0, agC0, fmaf(wins, hsumP, zb_e)));
      if (wv == 0 && (lane & 0x1E) == 0) {
        const size_t t0 = (size_t)(2 * j - 1);
        const int c = (lane >> 4) + (lane & 1);
        out[t0 * 4 + c] = (lane & 1) ? ybm : yam;
        out[(t0 + 1) * 4 + c] = (lane & 1) ? yb : ya;
      }
    }

    // ---- guesses (groups >=1) ----
    float yg1a = fmaf(h6_0, aaP0, ya), yg1b = fmaf(h6_0, abP0, yb);
    float zg1 = fmaf(h6_0, agP0, fmaf(wins, h0, zb_e));
    float yg2a = fmaf(h6_1, aaP1, yg1a), yg2b = fmaf(h6_1, abP1, yg1b);
    float zg2 = fmaf(h6_1, agP1, fmaf(wins, h1, zg1));
    float yg3a = fmaf(h6_2, aaP1, yg2a), yg3b = fmaf(h6_2, abP1, yg2b);
    float zg3 = fmaf(h6_2, agP1, fmaf(wins, h2, zg2));

    // ---- per-group eval ----
    float yA = (grp == 0) ? ya : (grp == 1) ? yg1a : (grp == 2) ? yg2a : yg3a;
    float yB = (grp == 0) ? yb : (grp == 1) ? yg1b : (grp == 2) ? yg2b : yg3b;
    float zB = (grp == 0) ? zb_e : (grp == 1) ? zg1 : (grp == 2) ? zg2 : zg3;
    float hg = (grp == 0) ? h0 : (grp == 1) ? h1 : (grp == 2) ? h2 : h3;
    float cw = (st == 0) ? 0.0f : (st == 3) ? hg : 0.5f * hg;

    setpref(fmaf(cw, kain, yA), fmaf(cw, kbin, yB));
    STAGE(fmaf(cw, gin, zB));
    wrslot(q, pfa * na, pfb * nb);

    h6p0 = h6_0; h6p1 = h6_1; hsumP = h0 + h1;

    __syncthreads();

    // roll s window (s[2j+2 .. 2j+6])
    s0 = s2; s1 = s3; s2 = s4;
    int bnext = 2 * j + 5;
    s3 = sat(bnext);
    s4 = sat(bnext + 1);
  }

  // ---- epilogue: y(T-1) from C(T-2) (slots 0..3 of buf NJ&1) ----
  {
    const int p = NJ & 1;
    float agE, aaE, abE;
    rd4(p, 0, agE, aaE, abE);
    (void)agE;
    float yaf = fmaf(h6p0, aaE, ya);
    float ybf = fmaf(h6p0, abE, yb);
    if (wv == 0 && (lane & 0x1E) == 0)
      out[(size_t)(T - 1) * 4 + (lane >> 4) + (lane & 1)] =
          (lane & 1) ? ybf : yaf;
  }
}

extern "C" void kernel_launch(void* const* d_in, const int* in_sizes, int n_in,
                              void* d_out, int out_size, void* d_ws, size_t ws_size,
                              hipStream_t stream) {
  const float* s_grid = (const float*)d_in[0];
  const float* y0 = (const float*)d_in[1];
  const float* Win = (const float*)d_in[2];
  const float* bin_ = (const float*)d_in[3];
  const float* W1a = (const float*)d_in[4];
  const float* b1a = (const float*)d_in[5];
  const float* W1b = (const float*)d_in[6];
  const float* b1b = (const float*)d_in[7];
  const float* W2a = (const float*)d_in[8];
  const float* b2a = (const float*)d_in[9];
  const float* W2b = (const float*)d_in[10];
  const float* b2b = (const float*)d_in[11];
  const float* Wout = (const float*)d_in[12];
  const float* bout = (const float*)d_in[13];
  const float* A = (const float*)d_in[14];
  int T = in_sizes[0];

  ode_kernel<<<1, 1024, 0, stream>>>(s_grid, y0, Win, bin_, W1a, b1a, W1b, b1b,
                                     W2a, b2a, W2b, b2b, Wout, bout, A,
                                     (float*)d_out, T);
}

// Round 14
// 2481.324 us; speedup vs baseline: 1.9339x; 1.9339x over previous
//
#include <hip/hip_runtime.h>

// PopulationODE: sequential RK4 scan, T=4096, state=4, HID=32.
// Round-14: EXTRAPOLATED stage inputs -> 4 waves, 4 evals/step (minimum).
//   r12/r13 diagnosis: ~80% VALU-busy on the active CU -> issue-bound by
//   the 8-eval predict+correct redundancy. Fix: stage s's inputs (gk, Ka,
//   Kb of stage s-1 at the SAME step) are obtained by linear extrapolation
//   from steps t-1, t-2 (err ~1e-7, vs r8's zero-order 1e-4 which measured
//   absmax 0.0 after one sweep). Sensitivity alpha ~ 1e-3 -> contraction.
//   All 4 stage evals of step t are then independent: wave s = stage s,
//   one eval + one lean LDS exchange (5 scalars/wave) + 1 barrier per step.
// Stage math identical to r7-r13 (g-form collapsed network).

__device__ __forceinline__ float fexp2(float x) { return __builtin_amdgcn_exp2f(x); }
__device__ __forceinline__ float frcp(float x) { return __builtin_amdgcn_rcpf(x); }
#define C_TANH 2.8853900817779268f
#define C_NSIG (-1.4426950408889634f)

template<int CTRL>
__device__ __forceinline__ float dppmov(float x) {
  return __int_as_float(__builtin_amdgcn_update_dpp(
      0, __float_as_int(x), CTRL, 0xF, 0xF, true));
}
#define RORc(K) (0x120 | (K))

__device__ __forceinline__ void p16swap(float& a, float& b) {
  asm("s_nop 1\n\tv_permlane16_swap_b32 %0, %1" : "+v"(a), "+v"(b));
}
__device__ __forceinline__ void p32swap(float& a, float& b) {
  asm("s_nop 1\n\tv_permlane32_swap_b32 %0, %1" : "+v"(a), "+v"(b));
}

#define MV8(W, BZ, X, SOUT) do {                                       \
    float b0_ = fmaf((X),             W[0], (BZ));                     \
    float b1_ = dppmov<RORc(1)>(X)  * W[1];                            \
    float b2_ = dppmov<RORc(2)>(X)  * W[2];                            \
    float b3_ = dppmov<RORc(3)>(X)  * W[3];                            \
    float b4_ = dppmov<RORc(4)>(X)  * W[4];                            \
    float b5_ = dppmov<RORc(5)>(X)  * W[5];                            \
    float b6_ = dppmov<RORc(6)>(X)  * W[6];                            \
    float b7_ = dppmov<RORc(7)>(X)  * W[7];                            \
    b0_ = fmaf(dppmov<RORc(8)>(X),  W[8],  b0_);                       \
    b1_ = fmaf(dppmov<RORc(9)>(X),  W[9],  b1_);                       \
    b2_ = fmaf(dppmov<RORc(10)>(X), W[10], b2_);                       \
    b3_ = fmaf(dppmov<RORc(11)>(X), W[11], b3_);                       \
    b4_ = fmaf(dppmov<RORc(12)>(X), W[12], b4_);                       \
    b5_ = fmaf(dppmov<RORc(13)>(X), W[13], b5_);                       \
    b6_ = fmaf(dppmov<RORc(14)>(X), W[14], b6_);                       \
    b7_ = fmaf(dppmov<RORc(15)>(X), W[15], b7_);                       \
    SOUT = ((b0_ + b1_) + (b2_ + b3_)) + ((b4_ + b5_) + (b6_ + b7_));  \
  } while (0)

__global__ __launch_bounds__(256, 1) __attribute__((amdgpu_waves_per_eu(1, 1)))
void ode_kernel(const float* __restrict__ s_grid,
                const float* __restrict__ y0in,
                const float* __restrict__ Win,
                const float* __restrict__ bin_,
                const float* __restrict__ W1a, const float* __restrict__ b1a,
                const float* __restrict__ W1b, const float* __restrict__ b1b,
                const float* __restrict__ W2a, const float* __restrict__ b2a,
                const float* __restrict__ W2b, const float* __restrict__ b2b,
                const float* __restrict__ Wout, const float* __restrict__ bout,
                const float* __restrict__ Aarr,
                float* __restrict__ out, int T) {
  const int tid = threadIdx.x;
  const int st = tid >> 6;        // wave = RK stage 0..3
  const int lane = tid & 63;
  const int i = lane & 15;
  const int m = lane >> 4;
  const int mlo = m & 1;
  const int mhi = m >> 1;

  // ---- LDS ----
  __shared__ float s_lds[4096];
  __shared__ float SC[2][4][8];   // [buf][stage]{K0,K1,K2,K3,gk,pad}
  for (int idx = tid; idx < T && idx < 4096; idx += 256)
    s_lds[idx] = s_grid[idx];
  __syncthreads();

  // ---- direction probes ----
  int delta;
  {
    float pr = (float)i;
    float pr1 = dppmov<RORc(1)>(pr);
    delta = (((int)pr1) - i) & 15;
  }
  bool p32_c_low;
  {
    float v = (float)(lane >> 5);
    float c = v, d = v;
    p32swap(c, d);
    p32_c_low = (c == 0.0f);
  }

  // ---- weight prep (identical to r7-r13) ----
  const int rA = 16 * mhi + i, hA = mlo;
  const int rB = 16 * mlo + i, hB = mhi;
  const int r_in = 16 * mlo + i;
  const int e1 = r_in;

  float w1a[16], w2a[16], m21[16];
#pragma unroll 1
  for (int k = 0; k < 16; ++k) {
    int cA = hA * 16 + ((i + delta * k) & 15);
    int cB = hB * 16 + ((i + delta * k) & 15);
    w1a[k] = W1a[rA * 32 + cA] * (-2.0f * C_TANH);
    w2a[k] = W2a[rA * 32 + cA] * (-2.0f * C_TANH);
    float acc = 0.0f;
    for (int q = 0; q < 32; ++q)
      acc = fmaf(W2a[rB * 32 + q], W1b[q * 32 + cB], acc);
    m21[k] = acc * (-2.0f * C_TANH);
  }
  float bz1a;
  {
    float rs = 0.0f;
    for (int c = 0; c < 32; ++c) rs += W1a[rA * 32 + c];
    bz1a = hA ? 0.0f : C_TANH * (b1a[rA] + rs);
  }
  float c2sel;
  {
    float rs2a = 0.0f, m21rs = 0.0f, wb = 0.0f;
    for (int q = 0; q < 32; ++q) {
      float w2q = W2a[rB * 32 + q];
      rs2a += w2q;
      float rs1bq = 0.0f;
      for (int c = 0; c < 32; ++c) rs1bq += W1b[q * 32 + c];
      m21rs = fmaf(w2q, rs1bq, m21rs);
      wb = fmaf(w2q, b1b[q], wb);
    }
    c2sel = hB ? 0.0f : C_TANH * (rs2a + m21rs + wb + b2a[rB]);
  }
  const bool seedsel = (mlo == mhi);

  float winy0 = Win[r_in * 5 + 0] * C_TANH;
  float winy1 = Win[r_in * 5 + 1] * C_TANH;
  float winy2 = Win[r_in * 5 + 2] * C_TANH;
  float winy3 = Win[r_in * 5 + 3] * C_TANH;
  float wins  = Win[r_in * 5 + 4] * C_TANH;
  float binr  = bin_[r_in] * C_TANH;
  float gsel_a = mhi ? winy2 : winy0;
  float gsel_b = mhi ? winy3 : winy1;

  const int ra_ = 2 * mhi, rb_ = 2 * mhi + 1;
  float woXa = Wout[ra_ * 32 + e1] * (-2.0f * C_NSIG);
  float woXb = Wout[rb_ * 32 + e1] * (-2.0f * C_NSIG);
  float wo1a, wo1b, wo2a, wo2b, boa, bob;
  {
    float w1s_a = 0.0f, w1s_b = 0.0f, w2s_a = 0.0f, w2s_b = 0.0f;
    float rsX_a = 0.0f, rsX_b = 0.0f, rs1_a = 0.0f, rs1_b = 0.0f;
    float rs2_a = 0.0f, rs2_b = 0.0f, bt_a = 0.0f, bt_b = 0.0f;
    for (int q = 0; q < 32; ++q) {
      float waq = Wout[ra_ * 32 + q], wbq = Wout[rb_ * 32 + q];
      w1s_a = fmaf(waq, W1b[q * 32 + e1], w1s_a);
      w1s_b = fmaf(wbq, W1b[q * 32 + e1], w1s_b);
      w2s_a = fmaf(waq, W2b[q * 32 + e1], w2s_a);
      w2s_b = fmaf(wbq, W2b[q * 32 + e1], w2s_b);
      rsX_a += waq; rsX_b += wbq;
      float rs1bq = 0.0f, rs2bq = 0.0f;
      for (int c = 0; c < 32; ++c) {
        rs1bq += W1b[q * 32 + c];
        rs2bq += W2b[q * 32 + c];
      }
      rs1_a = fmaf(waq, rs1bq, rs1_a); rs1_b = fmaf(wbq, rs1bq, rs1_b);
      rs2_a = fmaf(waq, rs2bq, rs2_a); rs2_b = fmaf(wbq, rs2bq, rs2_b);
      float bs = b1b[q] + b2b[q];
      bt_a = fmaf(waq, bs, bt_a); bt_b = fmaf(wbq, bs, bt_b);
    }
    wo1a = w1s_a * (-2.0f * C_NSIG); wo1b = w1s_b * (-2.0f * C_NSIG);
    wo2a = w2s_a * (-2.0f * C_NSIG); wo2b = w2s_b * (-2.0f * C_NSIG);
    boa = (bout[ra_] + bt_a + rsX_a + rs1_a + rs2_a) * (C_NSIG / 32.0f);
    bob = (bout[rb_] + bt_b + rsX_b + rs1_b + rs2_b) * (C_NSIG / 32.0f);
  }
  float Aa = mhi ? Aarr[2] : Aarr[0];
  float Ab = mhi ? Aarr[3] : Aarr[1];

  auto relayout = [&](float v) -> float {
    float c = v, d = v;
    p32swap(c, d);
    float lo = p32_c_low ? c : d;
    float hi = p32_c_low ? d : c;
    return mlo ? hi : lo;
  };

  float pfa, pfb, wpa, wpb, na, nb, gkv;

  auto setpref = [&](float yA, float yB) {
    float sa = frcp(1.0f + fexp2(yA * C_NSIG));
    float sb = frcp(1.0f + fexp2(yB * C_NSIG));
    pfa = 0.01f * sa * (Aa - sa);
    pfb = 0.01f * sb * (Ab - sb);
    wpa = gsel_a * pfa;
    wpb = gsel_b * pfb;
  };

  auto STAGE = [&](float zin) {
    float g0v = frcp(fexp2(zin) + 1.0f);                   // ABAB
    float u1; MV8(w1a, bz1a, g0v, u1);
    { float b = u1; p16swap(u1, b); u1 += b; }             // AABB
    float q2; MV8(w2a, 0.0f, g0v, q2);
    { float b = q2; p16swap(q2, b); q2 += b; }             // AABB
    float g1 = frcp(fexp2(u1) + 1.0f);
    float g1r = relayout(g1);
    float seed = (seedsel ? q2 : 0.0f) + c2sel;
    float u2; MV8(m21, seed, g1, u2);
    { float b = u2; p32swap(u2, b); u2 += b; }             // ABAB
    float g2 = frcp(fexp2(u2) + 1.0f);
    float ph0 = fmaf(wo1a, g1r, fmaf(woXa, g0v, boa));
    float ph1 = fmaf(wo1b, g1r, fmaf(woXb, g0v, bob));
    float p0 = fmaf(wo2a, g2, ph0);
    float p1 = fmaf(wo2b, g2, ph1);
    p0 += dppmov<RORc(8)>(p0); p1 += dppmov<RORc(8)>(p1);
    p0 += dppmov<RORc(4)>(p0); p1 += dppmov<RORc(4)>(p1);
    p0 += dppmov<RORc(2)>(p0); p1 += dppmov<RORc(2)>(p1);
    p0 += dppmov<RORc(1)>(p0); p1 += dppmov<RORc(1)>(p1);
    { float q = p0; p16swap(p0, q); p0 += q; }
    { float q = p1; p16swap(p1, q); p1 += q; }
    na = frcp(1.0f + fexp2(p0));
    nb = frcp(1.0f + fexp2(p1));
    float gp = fmaf(wpb, nb, wpa * na);
    float gq = gp;
    p32swap(gp, gq);
    gkv = gp + gq;
  };

  // ---- lean scalar exchange (r13 pattern) ----
  auto rdslot = [&](int pp, int ss, float& gk, float& ka, float& kb) {
    float2 kk = *reinterpret_cast<float2*>(&SC[pp][ss][mhi << 1]);
    ka = kk.x; kb = kk.y;
    gk = SC[pp][ss][4];
  };
  auto rd4 = [&](int pp, float& ag, float& aa, float& ab) {
    float g, a, b;
    rdslot(pp, 0, g, a, b); ag = g; aa = a; ab = b;
    rdslot(pp, 1, g, a, b);
    ag = fmaf(2.0f, g, ag); aa = fmaf(2.0f, a, aa); ab = fmaf(2.0f, b, ab);
    rdslot(pp, 2, g, a, b);
    ag = fmaf(2.0f, g, ag); aa = fmaf(2.0f, a, aa); ab = fmaf(2.0f, b, ab);
    rdslot(pp, 3, g, a, b); ag += g; aa += a; ab += b;
  };
  auto wrslot = [&](int qq, float Ka, float Kb) {
    float c0 = Ka, d0 = Ka; p32swap(c0, d0);
    float hiKa = p32_c_low ? d0 : c0;
    float c1 = Kb, d1 = Kb; p32swap(c1, d1);
    float hiKb = p32_c_low ? d1 : c1;
    if (lane == 0) {
      *reinterpret_cast<float4*>(&SC[qq][st][0]) =
          make_float4(Ka, Kb, hiKa, hiKb);   // K0,K1,K2,K3
      SC[qq][st][4] = gkv;
    }
  };

  // ---- state (every wave tracks identically) ----
  float y00 = y0in[0], y01 = y0in[1], y02 = y0in[2], y03 = y0in[3];
  float ya = mhi ? y02 : y00;
  float yb = mhi ? y03 : y01;

  if (st == 0 && (lane & 0x1E) == 0)
    out[(lane >> 4) + (lane & 1)] = (lane & 1) ? yb : ya;

  float sp = s_lds[0];
  float sn = (T > 1) ? s_lds[1] : sp;

  float zb = fmaf(winy0, y00, fmaf(winy1, y01, fmaf(winy2, y02,
             fmaf(winy3, y03, fmaf(wins, sp, binr)))));

  // ---- prologue: zero-input sweep -> approx step-0 stage outputs ----
  setpref(ya, yb);
  STAGE(zb);
  wrslot(0, pfa * na, pfb * nb);
  __syncthreads();

  // extrapolation history for stage st-1 outputs (t-2 values)
  float pg = 0.0f, pa = 0.0f, pb = 0.0f;
  float h6p = 0.0f, zbwp = 0.0f;

  for (int t = 0; t < T - 1; ++t) {
    const int p = t & 1, q = p ^ 1;
    const int i2 = (t + 2 < T) ? (t + 2) : (T - 1);
    float snn = s_lds[i2];

    // ---- read: own stage input history + full combine (for y update) ----
    float curg, cura, curb;
    rdslot(p, st ? st - 1 : 0, curg, cura, curb);
    if (t) {
      float agC, aaC, abC;
      rd4(p, agC, aaC, abC);
      ya = fmaf(h6p, aaC, ya);
      yb = fmaf(h6p, abC, yb);
      zb = fmaf(h6p, agC, zbwp);
      if (st == 0 && (lane & 0x1E) == 0)
        out[(size_t)t * 4 + (lane >> 4) + (lane & 1)] = (lane & 1) ? yb : ya;
    } else {
      pg = curg; pa = cura; pb = curb;   // bootstrap: zero-order at t=0
    }

    // ---- extrapolated same-step stage inputs (err ~1e-7) ----
    float gin  = 2.0f * curg - pg;
    float kain = 2.0f * cura - pa;
    float kbin = 2.0f * curb - pb;
    pg = curg; pa = cura; pb = curb;

    float h = sn - sp;
    float hh = 0.5f * h;
    float h6 = h * (1.0f / 6.0f);
    float cw = (st == 0) ? 0.0f : (st == 3) ? h : hh;

    setpref(fmaf(cw, kain, ya), fmaf(cw, kbin, yb));
    STAGE(fmaf(cw, gin, zb));
    wrslot(q, pfa * na, pfb * nb);

    h6p = h6;
    zbwp = fmaf(wins, h, zb);
    __syncthreads();

    sp = sn;
    sn = snn;
  }

  // ---- epilogue: finalize y(T-1) ----
  {
    const int p = (T - 1) & 1;
    float agE, aaE, abE;
    rd4(p, agE, aaE, abE);
    (void)agE;
    float yaf = fmaf(h6p, aaE, ya);
    float ybf = fmaf(h6p, abE, yb);
    if (st == 0 && (lane & 0x1E) == 0)
      out[(size_t)(T - 1) * 4 + (lane >> 4) + (lane & 1)] =
          (lane & 1) ? ybf : yaf;
  }
}

extern "C" void kernel_launch(void* const* d_in, const int* in_sizes, int n_in,
                              void* d_out, int out_size, void* d_ws, size_t ws_size,
                              hipStream_t stream) {
  const float* s_grid = (const float*)d_in[0];
  const float* y0 = (const float*)d_in[1];
  const float* Win = (const float*)d_in[2];
  const float* bin_ = (const float*)d_in[3];
  const float* W1a = (const float*)d_in[4];
  const float* b1a = (const float*)d_in[5];
  const float* W1b = (const float*)d_in[6];
  const float* b1b = (const float*)d_in[7];
  const float* W2a = (const float*)d_in[8];
  const float* b2a = (const float*)d_in[9];
  const float* W2b = (const float*)d_in[10];
  const float* b2b = (const float*)d_in[11];
  const float* Wout = (const float*)d_in[12];
  const float* bout = (const float*)d_in[13];
  const float* A = (const float*)d_in[14];
  int T = in_sizes[0];

  ode_kernel<<<1, 256, 0, stream>>>(s_grid, y0, Win, bin_, W1a, b1a, W1b, b1b,
                                    W2a, b2a, W2b, b2b, Wout, bout, A,
                                    (float*)d_out, T);
}

// Round 15
// 2323.915 us; speedup vs baseline: 2.0649x; 1.0677x over previous
//
#include <hip/hip_runtime.h>

// PopulationODE: sequential RK4 scan, T=4096, state=4, HID=32.
// Round-15: TWO STEPS IN FLIGHT (8 waves), extrapolated inputs.
//   grp0 (waves 0-3): step 2j,   exact y(2j) (r14 semantics)
//   grp1 (waves 4-7): step 2j+1, y/zb from extrapolated combine of step 2j,
//                     stage inputs extrapolated 2 steps (3g1-2g0).
//   One lean exchange (5 scalars/wave) + ONE barrier per TWO steps.
//   A- and B-waves share each SIMD -> eval latencies mutually hide.
// Numerics lineage: r8 zero-order guesses -> absmax 0.0; r14 1-step
// extrapolation -> 0.0078. Stage math identical to r7-r14.

__device__ __forceinline__ float fexp2(float x) { return __builtin_amdgcn_exp2f(x); }
__device__ __forceinline__ float frcp(float x) { return __builtin_amdgcn_rcpf(x); }
#define C_TANH 2.8853900817779268f
#define C_NSIG (-1.4426950408889634f)

template<int CTRL>
__device__ __forceinline__ float dppmov(float x) {
  return __int_as_float(__builtin_amdgcn_update_dpp(
      0, __float_as_int(x), CTRL, 0xF, 0xF, true));
}
#define RORc(K) (0x120 | (K))

__device__ __forceinline__ void p16swap(float& a, float& b) {
  asm("s_nop 1\n\tv_permlane16_swap_b32 %0, %1" : "+v"(a), "+v"(b));
}
__device__ __forceinline__ void p32swap(float& a, float& b) {
  asm("s_nop 1\n\tv_permlane32_swap_b32 %0, %1" : "+v"(a), "+v"(b));
}

#define MV8(W, BZ, X, SOUT) do {                                       \
    float b0_ = fmaf((X),             W[0], (BZ));                     \
    float b1_ = dppmov<RORc(1)>(X)  * W[1];                            \
    float b2_ = dppmov<RORc(2)>(X)  * W[2];                            \
    float b3_ = dppmov<RORc(3)>(X)  * W[3];                            \
    float b4_ = dppmov<RORc(4)>(X)  * W[4];                            \
    float b5_ = dppmov<RORc(5)>(X)  * W[5];                            \
    float b6_ = dppmov<RORc(6)>(X)  * W[6];                            \
    float b7_ = dppmov<RORc(7)>(X)  * W[7];                            \
    b0_ = fmaf(dppmov<RORc(8)>(X),  W[8],  b0_);                       \
    b1_ = fmaf(dppmov<RORc(9)>(X),  W[9],  b1_);                       \
    b2_ = fmaf(dppmov<RORc(10)>(X), W[10], b2_);                       \
    b3_ = fmaf(dppmov<RORc(11)>(X), W[11], b3_);                       \
    b4_ = fmaf(dppmov<RORc(12)>(X), W[12], b4_);                       \
    b5_ = fmaf(dppmov<RORc(13)>(X), W[13], b5_);                       \
    b6_ = fmaf(dppmov<RORc(14)>(X), W[14], b6_);                       \
    b7_ = fmaf(dppmov<RORc(15)>(X), W[15], b7_);                       \
    SOUT = ((b0_ + b1_) + (b2_ + b3_)) + ((b4_ + b5_) + (b6_ + b7_));  \
  } while (0)

__global__ __launch_bounds__(512, 1) __attribute__((amdgpu_waves_per_eu(2, 2)))
void ode_kernel(const float* __restrict__ s_grid,
                const float* __restrict__ y0in,
                const float* __restrict__ Win,
                const float* __restrict__ bin_,
                const float* __restrict__ W1a, const float* __restrict__ b1a,
                const float* __restrict__ W1b, const float* __restrict__ b1b,
                const float* __restrict__ W2a, const float* __restrict__ b2a,
                const float* __restrict__ W2b, const float* __restrict__ b2b,
                const float* __restrict__ Wout, const float* __restrict__ bout,
                const float* __restrict__ Aarr,
                float* __restrict__ out, int T) {
  const int tid = threadIdx.x;
  const int wv = tid >> 6;        // 0..7
  const int grp = wv >> 2;        // 0: step 2j, 1: step 2j+1
  const int st = wv & 3;          // RK stage owned
  const int lane = tid & 63;
  const int i = lane & 15;
  const int m = lane >> 4;
  const int mlo = m & 1;
  const int mhi = m >> 1;

  // ---- LDS ----
  __shared__ float s_lds[4096];
  __shared__ float SC[2][8][8];   // [buf][slot=wv]{K0,K1,K2,K3,gk,pad}
  for (int idx = tid; idx < T && idx < 4096; idx += 512)
    s_lds[idx] = s_grid[idx];
  __syncthreads();

  // ---- direction probes ----
  int delta;
  {
    float pr = (float)i;
    float pr1 = dppmov<RORc(1)>(pr);
    delta = (((int)pr1) - i) & 15;
  }
  bool p32_c_low;
  {
    float v = (float)(lane >> 5);
    float c = v, d = v;
    p32swap(c, d);
    p32_c_low = (c == 0.0f);
  }

  // ---- weight prep (identical to r7-r14) ----
  const int rA = 16 * mhi + i, hA = mlo;
  const int rB = 16 * mlo + i, hB = mhi;
  const int r_in = 16 * mlo + i;
  const int e1 = r_in;

  float w1a[16], w2a[16], m21[16];
#pragma unroll 1
  for (int k = 0; k < 16; ++k) {
    int cA = hA * 16 + ((i + delta * k) & 15);
    int cB = hB * 16 + ((i + delta * k) & 15);
    w1a[k] = W1a[rA * 32 + cA] * (-2.0f * C_TANH);
    w2a[k] = W2a[rA * 32 + cA] * (-2.0f * C_TANH);
    float acc = 0.0f;
    for (int q = 0; q < 32; ++q)
      acc = fmaf(W2a[rB * 32 + q], W1b[q * 32 + cB], acc);
    m21[k] = acc * (-2.0f * C_TANH);
  }
  float bz1a;
  {
    float rs = 0.0f;
    for (int c = 0; c < 32; ++c) rs += W1a[rA * 32 + c];
    bz1a = hA ? 0.0f : C_TANH * (b1a[rA] + rs);
  }
  float c2sel;
  {
    float rs2a = 0.0f, m21rs = 0.0f, wb = 0.0f;
    for (int q = 0; q < 32; ++q) {
      float w2q = W2a[rB * 32 + q];
      rs2a += w2q;
      float rs1bq = 0.0f;
      for (int c = 0; c < 32; ++c) rs1bq += W1b[q * 32 + c];
      m21rs = fmaf(w2q, rs1bq, m21rs);
      wb = fmaf(w2q, b1b[q], wb);
    }
    c2sel = hB ? 0.0f : C_TANH * (rs2a + m21rs + wb + b2a[rB]);
  }
  const bool seedsel = (mlo == mhi);

  float winy0 = Win[r_in * 5 + 0] * C_TANH;
  float winy1 = Win[r_in * 5 + 1] * C_TANH;
  float winy2 = Win[r_in * 5 + 2] * C_TANH;
  float winy3 = Win[r_in * 5 + 3] * C_TANH;
  float wins  = Win[r_in * 5 + 4] * C_TANH;
  float binr  = bin_[r_in] * C_TANH;
  float gsel_a = mhi ? winy2 : winy0;
  float gsel_b = mhi ? winy3 : winy1;

  const int ra_ = 2 * mhi, rb_ = 2 * mhi + 1;
  float woXa = Wout[ra_ * 32 + e1] * (-2.0f * C_NSIG);
  float woXb = Wout[rb_ * 32 + e1] * (-2.0f * C_NSIG);
  float wo1a, wo1b, wo2a, wo2b, boa, bob;
  {
    float w1s_a = 0.0f, w1s_b = 0.0f, w2s_a = 0.0f, w2s_b = 0.0f;
    float rsX_a = 0.0f, rsX_b = 0.0f, rs1_a = 0.0f, rs1_b = 0.0f;
    float rs2_a = 0.0f, rs2_b = 0.0f, bt_a = 0.0f, bt_b = 0.0f;
    for (int q = 0; q < 32; ++q) {
      float waq = Wout[ra_ * 32 + q], wbq = Wout[rb_ * 32 + q];
      w1s_a = fmaf(waq, W1b[q * 32 + e1], w1s_a);
      w1s_b = fmaf(wbq, W1b[q * 32 + e1], w1s_b);
      w2s_a = fmaf(waq, W2b[q * 32 + e1], w2s_a);
      w2s_b = fmaf(wbq, W2b[q * 32 + e1], w2s_b);
      rsX_a += waq; rsX_b += wbq;
      float rs1bq = 0.0f, rs2bq = 0.0f;
      for (int c = 0; c < 32; ++c) {
        rs1bq += W1b[q * 32 + c];
        rs2bq += W2b[q * 32 + c];
      }
      rs1_a = fmaf(waq, rs1bq, rs1_a); rs1_b = fmaf(wbq, rs1bq, rs1_b);
      rs2_a = fmaf(waq, rs2bq, rs2_a); rs2_b = fmaf(wbq, rs2bq, rs2_b);
      float bs = b1b[q] + b2b[q];
      bt_a = fmaf(waq, bs, bt_a); bt_b = fmaf(wbq, bs, bt_b);
    }
    wo1a = w1s_a * (-2.0f * C_NSIG); wo1b = w1s_b * (-2.0f * C_NSIG);
    wo2a = w2s_a * (-2.0f * C_NSIG); wo2b = w2s_b * (-2.0f * C_NSIG);
    boa = (bout[ra_] + bt_a + rsX_a + rs1_a + rs2_a) * (C_NSIG / 32.0f);
    bob = (bout[rb_] + bt_b + rsX_b + rs1_b + rs2_b) * (C_NSIG / 32.0f);
  }
  float Aa = mhi ? Aarr[2] : Aarr[0];
  float Ab = mhi ? Aarr[3] : Aarr[1];

  auto relayout = [&](float v) -> float {
    float c = v, d = v;
    p32swap(c, d);
    float lo = p32_c_low ? c : d;
    float hi = p32_c_low ? d : c;
    return mlo ? hi : lo;
  };

  float pfa, pfb, wpa, wpb, na, nb, gkv;

  auto setpref = [&](float yA, float yB) {
    float sa = frcp(1.0f + fexp2(yA * C_NSIG));
    float sb = frcp(1.0f + fexp2(yB * C_NSIG));
    pfa = 0.01f * sa * (Aa - sa);
    pfb = 0.01f * sb * (Ab - sb);
    wpa = gsel_a * pfa;
    wpb = gsel_b * pfb;
  };

  auto STAGE = [&](float zin) {
    float g0v = frcp(fexp2(zin) + 1.0f);                   // ABAB
    float u1; MV8(w1a, bz1a, g0v, u1);
    { float b = u1; p16swap(u1, b); u1 += b; }             // AABB
    float q2; MV8(w2a, 0.0f, g0v, q2);
    { float b = q2; p16swap(q2, b); q2 += b; }             // AABB
    float g1 = frcp(fexp2(u1) + 1.0f);
    float g1r = relayout(g1);
    float seed = (seedsel ? q2 : 0.0f) + c2sel;
    float u2; MV8(m21, seed, g1, u2);
    { float b = u2; p32swap(u2, b); u2 += b; }             // ABAB
    float g2 = frcp(fexp2(u2) + 1.0f);
    float ph0 = fmaf(wo1a, g1r, fmaf(woXa, g0v, boa));
    float ph1 = fmaf(wo1b, g1r, fmaf(woXb, g0v, bob));
    float p0 = fmaf(wo2a, g2, ph0);
    float p1 = fmaf(wo2b, g2, ph1);
    p0 += dppmov<RORc(8)>(p0); p1 += dppmov<RORc(8)>(p1);
    p0 += dppmov<RORc(4)>(p0); p1 += dppmov<RORc(4)>(p1);
    p0 += dppmov<RORc(2)>(p0); p1 += dppmov<RORc(2)>(p1);
    p0 += dppmov<RORc(1)>(p0); p1 += dppmov<RORc(1)>(p1);
    { float q = p0; p16swap(p0, q); p0 += q; }
    { float q = p1; p16swap(p1, q); p1 += q; }
    na = frcp(1.0f + fexp2(p0));
    nb = frcp(1.0f + fexp2(p1));
    float gp = fmaf(wpb, nb, wpa * na);
    float gq = gp;
    p32swap(gp, gq);
    gkv = gp + gq;
  };

  // ---- lean scalar exchange ----
  auto rdslot = [&](int pp, int ss, float& gk, float& ka, float& kb) {
    float2 kk = *reinterpret_cast<float2*>(&SC[pp][ss][mhi << 1]);
    ka = kk.x; kb = kk.y;
    gk = SC[pp][ss][4];
  };
  auto rd4 = [&](int pp, int base, float& ag, float& aa, float& ab) {
    float g, a, b;
    rdslot(pp, base + 0, g, a, b); ag = g; aa = a; ab = b;
    rdslot(pp, base + 1, g, a, b);
    ag = fmaf(2.0f, g, ag); aa = fmaf(2.0f, a, aa); ab = fmaf(2.0f, b, ab);
    rdslot(pp, base + 2, g, a, b);
    ag = fmaf(2.0f, g, ag); aa = fmaf(2.0f, a, aa); ab = fmaf(2.0f, b, ab);
    rdslot(pp, base + 3, g, a, b); ag += g; aa += a; ab += b;
  };
  auto wrslot = [&](int qq, float Ka, float Kb) {
    float c0 = Ka, d0 = Ka; p32swap(c0, d0);
    float hiKa = p32_c_low ? d0 : c0;
    float c1 = Kb, d1 = Kb; p32swap(c1, d1);
    float hiKb = p32_c_low ? d1 : c1;
    if (lane == 0) {
      *reinterpret_cast<float4*>(&SC[qq][wv][0]) =
          make_float4(Ka, Kb, hiKa, hiKb);   // K0,K1,K2,K3
      SC[qq][wv][4] = gkv;
    }
  };

  // ---- state (every wave tracks identically; lags the pipeline) ----
  float y00 = y0in[0], y01 = y0in[1], y02 = y0in[2], y03 = y0in[3];
  float ya = mhi ? y02 : y00;
  float yb = mhi ? y03 : y01;

  if (wv == 0 && (lane & 0x1E) == 0)
    out[(lane >> 4) + (lane & 1)] = (lane & 1) ? yb : ya;

  float zb = fmaf(winy0, y00, fmaf(winy1, y01, fmaf(winy2, y02,
             fmaf(winy3, y03, fmaf(wins, s_lds[0], binr)))));

  // ---- prologue: zero-input sweeps seed buf[1] (pseudo prev-steps) ----
  {
    float s0v = s_lds[0];
    float s1v = (T > 1) ? s_lds[1] : s0v;
    float h0 = s1v - s0v;
    setpref(ya, yb);
    STAGE(grp ? fmaf(wins, h0, zb) : zb);
    wrslot(1, pfa * na, pfb * nb);
  }
  __syncthreads();

  float h6p0 = 0.0f, h6p1 = 0.0f, hsumP = 0.0f;
  const int NJ = T >> 1;   // iterations; steps 2j, 2j+1 (last B-step dummy)

  for (int j = 0; j < NJ; ++j) {
    const int w = j & 1, r = w ^ 1;
    int i0 = 2 * j, i1 = 2 * j + 1, i2v = 2 * j + 2;
    float s0v = s_lds[i0];
    float s1v = s_lds[i1 < T ? i1 : T - 1];
    float s2v = s_lds[i2v < T ? i2v : T - 1];
    float h0 = s1v - s0v, h1 = s2v - s1v;
    float h6_0 = h0 * (1.0f / 6.0f), h6_1 = h1 * (1.0f / 6.0f);

    // ---- reads from buf r (steps 2j-2, 2j-1) ----
    float gC0, aC0, bC0, gC1, aC1, bC1;
    rd4(r, 0, gC0, aC0, bC0);
    rd4(r, 4, gC1, aC1, bC1);
    const int sl = st ? st - 1 : 0;
    float g0i, a0i, b0i, g1i, a1i, b1i;
    rdslot(r, sl, g0i, a0i, b0i);
    rdslot(r, 4 + sl, g1i, a1i, b1i);

    // ---- finalize exact y(2j-1), y(2j) (j>=1) ----
    if (j) {
      float yam = fmaf(h6p0, aC0, ya);
      float ybm = fmaf(h6p0, bC0, yb);
      ya = fmaf(h6p1, aC1, yam);
      yb = fmaf(h6p1, bC1, ybm);
      zb = fmaf(h6p1, gC1, fmaf(h6p0, gC0, fmaf(wins, hsumP, zb)));
      if (wv == 0 && (lane & 0x1E) == 0) {
        const size_t t0 = (size_t)(2 * j - 1);
        const int c = (lane >> 4) + (lane & 1);
        out[t0 * 4 + c] = (lane & 1) ? ybm : yam;
        out[(t0 + 1) * 4 + c] = (lane & 1) ? yb : ya;
      }
    }

    // ---- extrapolated same-step stage inputs ----
    float gin, kain, kbin;
    if (grp == 0) {                      // 1 step past step 2j-1
      gin = 2.0f * g1i - g0i;
      kain = 2.0f * a1i - a0i;
      kbin = 2.0f * b1i - b0i;
    } else {                             // 2 steps past step 2j-1
      gin = 3.0f * g1i - 2.0f * g0i;
      kain = 3.0f * a1i - 2.0f * a0i;
      kbin = 3.0f * b1i - 2.0f * b0i;
    }

    // ---- y/zb for the eval ----
    float yA, yB, zB, hg;
    if (grp == 0) {
      yA = ya; yB = yb; zB = zb; hg = h0;
    } else {
      float cga = 2.0f * aC1 - aC0;      // extrapolated combine of step 2j
      float cgb = 2.0f * bC1 - bC0;
      float cgg = 2.0f * gC1 - gC0;
      yA = fmaf(h6_0, cga, ya);
      yB = fmaf(h6_0, cgb, yb);
      zB = fmaf(h6_0, cgg, fmaf(wins, h0, zb));
      hg = h1;
    }
    float cw = (st == 0) ? 0.0f : (st == 3) ? hg : 0.5f * hg;

    setpref(fmaf(cw, kain, yA), fmaf(cw, kbin, yB));
    STAGE(fmaf(cw, gin, zB));
    wrslot(w, pfa * na, pfb * nb);

    h6p0 = h6_0; h6p1 = h6_1; hsumP = h0 + h1;
    __syncthreads();
  }

  // ---- epilogue: y(T-1) from C(T-2) (slots 0-3 of last-written buf) ----
  if (T > 1) {
    const int r = (NJ - 1) & 1;
    float gE, aE, bE;
    rd4(r, 0, gE, aE, bE);
    (void)gE;
    float yaf = fmaf(h6p0, aE, ya);
    float ybf = fmaf(h6p0, bE, yb);
    if (wv == 0 && (lane & 0x1E) == 0)
      out[(size_t)(T - 1) * 4 + (lane >> 4) + (lane & 1)] =
          (lane & 1) ? ybf : yaf;
  }
}

extern "C" void kernel_launch(void* const* d_in, const int* in_sizes, int n_in,
                              void* d_out, int out_size, void* d_ws, size_t ws_size,
                              hipStream_t stream) {
  const float* s_grid = (const float*)d_in[0];
  const float* y0 = (const float*)d_in[1];
  const float* Win = (const float*)d_in[2];
  const float* bin_ = (const float*)d_in[3];
  const float* W1a = (const float*)d_in[4];
  const float* b1a = (const float*)d_in[5];
  const float* W1b = (const float*)d_in[6];
  const float* b1b = (const float*)d_in[7];
  const float* W2a = (const float*)d_in[8];
  const float* b2a = (const float*)d_in[9];
  const float* W2b = (const float*)d_in[10];
  const float* b2b = (const float*)d_in[11];
  const float* Wout = (const float*)d_in[12];
  const float* bout = (const float*)d_in[13];
  const float* A = (const float*)d_in[14];
  int T = in_sizes[0];

  ode_kernel<<<1, 512, 0, stream>>>(s_grid, y0, Win, bin_, W1a, b1a, W1b, b1b,
                                    W2a, b2a, W2b, b2b, Wout, bout, A,
                                    (float*)d_out, T);
}

// Round 16
// 1964.439 us; speedup vs baseline: 2.4427x; 1.1830x over previous
//
#include <hip/hip_runtime.h>

// PopulationODE: sequential RK4 scan, T=4096, state=4, HID=32.
// Round-16: r15 structure (8 waves, 2 steps in flight, extrapolated
// inputs) with two instruction-count cuts, math BIT-IDENTICAL to r15:
//   1) MV8 in inline asm: guaranteed v_mul_f32_dpp / v_fmac_f32_dpp
//      (16 MACs in 16 instrs; no dependence on GCNDPPCombine firing).
//   2) Packed LDS exchange: PK[2][2][8] float2 + GK[2][8]; readers use
//      4+2 b128 broadcast loads (+2 scalar own-slot reads) vs 20 scalar
//      ops; writers store b64 directly from lanes 0/32 (drops 2 p32swaps).

__device__ __forceinline__ float fexp2(float x) { return __builtin_amdgcn_exp2f(x); }
__device__ __forceinline__ float frcp(float x) { return __builtin_amdgcn_rcpf(x); }
#define C_TANH 2.8853900817779268f
#define C_NSIG (-1.4426950408889634f)

template<int CTRL>
__device__ __forceinline__ float dppmov(float x) {
  return __int_as_float(__builtin_amdgcn_update_dpp(
      0, __float_as_int(x), CTRL, 0xF, 0xF, true));
}
#define RORc(K) (0x120 | (K))

__device__ __forceinline__ void p16swap(float& a, float& b) {
  asm("s_nop 1\n\tv_permlane16_swap_b32 %0, %1" : "+v"(a), "+v"(b));
}
__device__ __forceinline__ void p32swap(float& a, float& b) {
  asm("s_nop 1\n\tv_permlane32_swap_b32 %0, %1" : "+v"(a), "+v"(b));
}

// 16 MACs, 8 streams (stream j: rotation j and j+8), guaranteed DPP-fused.
// Association identical to r7-r15's MV8: b0 seeded with BZ via fmaf.
#define MV8(W, BZ, X, SOUT) do {                                            \
    float b0_ = fmaf((X), W[0], (BZ));                                      \
    float b1_, b2_, b3_, b4_, b5_, b6_, b7_;                                \
    asm("s_nop 1\n\t"                                                       \
        "v_mul_f32_dpp %1, %8, %9 row_ror:1 row_mask:0xf bank_mask:0xf\n\t" \
        "v_mul_f32_dpp %2, %8, %10 row_ror:2 row_mask:0xf bank_mask:0xf\n\t"\
        "v_mul_f32_dpp %3, %8, %11 row_ror:3 row_mask:0xf bank_mask:0xf\n\t"\
        "v_mul_f32_dpp %4, %8, %12 row_ror:4 row_mask:0xf bank_mask:0xf\n\t"\
        "v_mul_f32_dpp %5, %8, %13 row_ror:5 row_mask:0xf bank_mask:0xf\n\t"\
        "v_mul_f32_dpp %6, %8, %14 row_ror:6 row_mask:0xf bank_mask:0xf\n\t"\
        "v_mul_f32_dpp %7, %8, %15 row_ror:7 row_mask:0xf bank_mask:0xf\n\t"\
        "v_fmac_f32_dpp %0, %8, %16 row_ror:8 row_mask:0xf bank_mask:0xf\n\t"\
        "v_fmac_f32_dpp %1, %8, %17 row_ror:9 row_mask:0xf bank_mask:0xf\n\t"\
        "v_fmac_f32_dpp %2, %8, %18 row_ror:10 row_mask:0xf bank_mask:0xf\n\t"\
        "v_fmac_f32_dpp %3, %8, %19 row_ror:11 row_mask:0xf bank_mask:0xf\n\t"\
        "v_fmac_f32_dpp %4, %8, %20 row_ror:12 row_mask:0xf bank_mask:0xf\n\t"\
        "v_fmac_f32_dpp %5, %8, %21 row_ror:13 row_mask:0xf bank_mask:0xf\n\t"\
        "v_fmac_f32_dpp %6, %8, %22 row_ror:14 row_mask:0xf bank_mask:0xf\n\t"\
        "v_fmac_f32_dpp %7, %8, %23 row_ror:15 row_mask:0xf bank_mask:0xf"  \
        : "+v"(b0_), "=&v"(b1_), "=&v"(b2_), "=&v"(b3_),                    \
          "=&v"(b4_), "=&v"(b5_), "=&v"(b6_), "=&v"(b7_)                    \
        : "v"(X), "v"(W[1]), "v"(W[2]), "v"(W[3]), "v"(W[4]),               \
          "v"(W[5]), "v"(W[6]), "v"(W[7]), "v"(W[8]), "v"(W[9]),            \
          "v"(W[10]), "v"(W[11]), "v"(W[12]), "v"(W[13]), "v"(W[14]),       \
          "v"(W[15]));                                                      \
    SOUT = ((b0_ + b1_) + (b2_ + b3_)) + ((b4_ + b5_) + (b6_ + b7_));       \
  } while (0)

__global__ __launch_bounds__(512, 1) __attribute__((amdgpu_waves_per_eu(2, 2)))
void ode_kernel(const float* __restrict__ s_grid,
                const float* __restrict__ y0in,
                const float* __restrict__ Win,
                const float* __restrict__ bin_,
                const float* __restrict__ W1a, const float* __restrict__ b1a,
                const float* __restrict__ W1b, const float* __restrict__ b1b,
                const float* __restrict__ W2a, const float* __restrict__ b2a,
                const float* __restrict__ W2b, const float* __restrict__ b2b,
                const float* __restrict__ Wout, const float* __restrict__ bout,
                const float* __restrict__ Aarr,
                float* __restrict__ out, int T) {
  const int tid = threadIdx.x;
  const int wv = tid >> 6;        // 0..7
  const int grp = wv >> 2;        // 0: step 2j, 1: step 2j+1
  const int st = wv & 3;          // RK stage owned
  const int lane = tid & 63;
  const int i = lane & 15;
  const int m = lane >> 4;
  const int mlo = m & 1;
  const int mhi = m >> 1;

  // ---- LDS ----
  __shared__ float s_lds[4096];
  __shared__ __align__(16) float2 PK[2][2][8];  // [buf][half][slot]=(K2h,K2h+1)
  __shared__ __align__(16) float GK[2][8];      // [buf][slot]=gk
  for (int idx = tid; idx < T && idx < 4096; idx += 512)
    s_lds[idx] = s_grid[idx];
  __syncthreads();

  // ---- direction probes ----
  int delta;
  {
    float pr = (float)i;
    float pr1 = dppmov<RORc(1)>(pr);
    delta = (((int)pr1) - i) & 15;
  }
  bool p32_c_low;
  {
    float v = (float)(lane >> 5);
    float c = v, d = v;
    p32swap(c, d);
    p32_c_low = (c == 0.0f);
  }

  // ---- weight prep (identical to r7-r15) ----
  const int rA = 16 * mhi + i, hA = mlo;
  const int rB = 16 * mlo + i, hB = mhi;
  const int r_in = 16 * mlo + i;
  const int e1 = r_in;

  float w1a[16], w2a[16], m21[16];
#pragma unroll 1
  for (int k = 0; k < 16; ++k) {
    int cA = hA * 16 + ((i + delta * k) & 15);
    int cB = hB * 16 + ((i + delta * k) & 15);
    w1a[k] = W1a[rA * 32 + cA] * (-2.0f * C_TANH);
    w2a[k] = W2a[rA * 32 + cA] * (-2.0f * C_TANH);
    float acc = 0.0f;
    for (int q = 0; q < 32; ++q)
      acc = fmaf(W2a[rB * 32 + q], W1b[q * 32 + cB], acc);
    m21[k] = acc * (-2.0f * C_TANH);
  }
  float bz1a;
  {
    float rs = 0.0f;
    for (int c = 0; c < 32; ++c) rs += W1a[rA * 32 + c];
    bz1a = hA ? 0.0f : C_TANH * (b1a[rA] + rs);
  }
  float c2sel;
  {
    float rs2a = 0.0f, m21rs = 0.0f, wb = 0.0f;
    for (int q = 0; q < 32; ++q) {
      float w2q = W2a[rB * 32 + q];
      rs2a += w2q;
      float rs1bq = 0.0f;
      for (int c = 0; c < 32; ++c) rs1bq += W1b[q * 32 + c];
      m21rs = fmaf(w2q, rs1bq, m21rs);
      wb = fmaf(w2q, b1b[q], wb);
    }
    c2sel = hB ? 0.0f : C_TANH * (rs2a + m21rs + wb + b2a[rB]);
  }
  const bool seedsel = (mlo == mhi);

  float winy0 = Win[r_in * 5 + 0] * C_TANH;
  float winy1 = Win[r_in * 5 + 1] * C_TANH;
  float winy2 = Win[r_in * 5 + 2] * C_TANH;
  float winy3 = Win[r_in * 5 + 3] * C_TANH;
  float wins  = Win[r_in * 5 + 4] * C_TANH;
  float binr  = bin_[r_in] * C_TANH;
  float gsel_a = mhi ? winy2 : winy0;
  float gsel_b = mhi ? winy3 : winy1;

  const int ra_ = 2 * mhi, rb_ = 2 * mhi + 1;
  float woXa = Wout[ra_ * 32 + e1] * (-2.0f * C_NSIG);
  float woXb = Wout[rb_ * 32 + e1] * (-2.0f * C_NSIG);
  float wo1a, wo1b, wo2a, wo2b, boa, bob;
  {
    float w1s_a = 0.0f, w1s_b = 0.0f, w2s_a = 0.0f, w2s_b = 0.0f;
    float rsX_a = 0.0f, rsX_b = 0.0f, rs1_a = 0.0f, rs1_b = 0.0f;
    float rs2_a = 0.0f, rs2_b = 0.0f, bt_a = 0.0f, bt_b = 0.0f;
    for (int q = 0; q < 32; ++q) {
      float waq = Wout[ra_ * 32 + q], wbq = Wout[rb_ * 32 + q];
      w1s_a = fmaf(waq, W1b[q * 32 + e1], w1s_a);
      w1s_b = fmaf(wbq, W1b[q * 32 + e1], w1s_b);
      w2s_a = fmaf(waq, W2b[q * 32 + e1], w2s_a);
      w2s_b = fmaf(wbq, W2b[q * 32 + e1], w2s_b);
      rsX_a += waq; rsX_b += wbq;
      float rs1bq = 0.0f, rs2bq = 0.0f;
      for (int c = 0; c < 32; ++c) {
        rs1bq += W1b[q * 32 + c];
        rs2bq += W2b[q * 32 + c];
      }
      rs1_a = fmaf(waq, rs1bq, rs1_a); rs1_b = fmaf(wbq, rs1bq, rs1_b);
      rs2_a = fmaf(waq, rs2bq, rs2_a); rs2_b = fmaf(wbq, rs2bq, rs2_b);
      float bs = b1b[q] + b2b[q];
      bt_a = fmaf(waq, bs, bt_a); bt_b = fmaf(wbq, bs, bt_b);
    }
    wo1a = w1s_a * (-2.0f * C_NSIG); wo1b = w1s_b * (-2.0f * C_NSIG);
    wo2a = w2s_a * (-2.0f * C_NSIG); wo2b = w2s_b * (-2.0f * C_NSIG);
    boa = (bout[ra_] + bt_a + rsX_a + rs1_a + rs2_a) * (C_NSIG / 32.0f);
    bob = (bout[rb_] + bt_b + rsX_b + rs1_b + rs2_b) * (C_NSIG / 32.0f);
  }
  float Aa = mhi ? Aarr[2] : Aarr[0];
  float Ab = mhi ? Aarr[3] : Aarr[1];

  auto relayout = [&](float v) -> float {
    float c = v, d = v;
    p32swap(c, d);
    float lo = p32_c_low ? c : d;
    float hi = p32_c_low ? d : c;
    return mlo ? hi : lo;
  };

  float pfa, pfb, wpa, wpb, na, nb, gkv;

  auto setpref = [&](float yA, float yB) {
    float sa = frcp(1.0f + fexp2(yA * C_NSIG));
    float sb = frcp(1.0f + fexp2(yB * C_NSIG));
    pfa = 0.01f * sa * (Aa - sa);
    pfb = 0.01f * sb * (Ab - sb);
    wpa = gsel_a * pfa;
    wpb = gsel_b * pfb;
  };

  auto STAGE = [&](float zin) {
    float g0v = frcp(fexp2(zin) + 1.0f);                   // ABAB
    float u1; MV8(w1a, bz1a, g0v, u1);
    { float b = u1; p16swap(u1, b); u1 += b; }             // AABB
    float q2; MV8(w2a, 0.0f, g0v, q2);
    { float b = q2; p16swap(q2, b); q2 += b; }             // AABB
    float g1 = frcp(fexp2(u1) + 1.0f);
    float g1r = relayout(g1);
    float seed = (seedsel ? q2 : 0.0f) + c2sel;
    float u2; MV8(m21, seed, g1, u2);
    { float b = u2; p32swap(u2, b); u2 += b; }             // ABAB
    float g2 = frcp(fexp2(u2) + 1.0f);
    float ph0 = fmaf(wo1a, g1r, fmaf(woXa, g0v, boa));
    float ph1 = fmaf(wo1b, g1r, fmaf(woXb, g0v, bob));
    float p0 = fmaf(wo2a, g2, ph0);
    float p1 = fmaf(wo2b, g2, ph1);
    p0 += dppmov<RORc(8)>(p0); p1 += dppmov<RORc(8)>(p1);
    p0 += dppmov<RORc(4)>(p0); p1 += dppmov<RORc(4)>(p1);
    p0 += dppmov<RORc(2)>(p0); p1 += dppmov<RORc(2)>(p1);
    p0 += dppmov<RORc(1)>(p0); p1 += dppmov<RORc(1)>(p1);
    { float q = p0; p16swap(p0, q); p0 += q; }
    { float q = p1; p16swap(p1, q); p1 += q; }
    na = frcp(1.0f + fexp2(p0));
    nb = frcp(1.0f + fexp2(p1));
    float gp = fmaf(wpb, nb, wpa * na);
    float gq = gp;
    p32swap(gp, gq);
    gkv = gp + gq;
  };

  // packed exchange write: lane0 -> half 0 (K0,K1), lane32 -> half 1 (K2,K3)
  auto wrslot = [&](int qq, float Ka, float Kb) {
    if ((lane & 31) == 0)
      PK[qq][mhi][wv] = make_float2(Ka, Kb);
    if (lane == 0)
      GK[qq][wv] = gkv;
  };

  // ---- state (every wave tracks identically; lags the pipeline) ----
  float y00 = y0in[0], y01 = y0in[1], y02 = y0in[2], y03 = y0in[3];
  float ya = mhi ? y02 : y00;
  float yb = mhi ? y03 : y01;

  if (wv == 0 && (lane & 0x1E) == 0)
    out[(lane >> 4) + (lane & 1)] = (lane & 1) ? yb : ya;

  float zb = fmaf(winy0, y00, fmaf(winy1, y01, fmaf(winy2, y02,
             fmaf(winy3, y03, fmaf(wins, s_lds[0], binr)))));

  // ---- prologue: zero-input sweeps seed buf[1] ----
  {
    float s0v = s_lds[0];
    float s1v = (T > 1) ? s_lds[1] : s0v;
    float h0 = s1v - s0v;
    setpref(ya, yb);
    STAGE(grp ? fmaf(wins, h0, zb) : zb);
    wrslot(1, pfa * na, pfb * nb);
  }
  __syncthreads();

  float h6p0 = 0.0f, h6p1 = 0.0f, hsumP = 0.0f;
  const int NJ = T >> 1;

  for (int j = 0; j < NJ; ++j) {
    const int w = j & 1, r = w ^ 1;
    int i0 = 2 * j, i1 = 2 * j + 1, i2v = 2 * j + 2;
    float s0v = s_lds[i0];
    float s1v = s_lds[i1 < T ? i1 : T - 1];
    float s2v = s_lds[i2v < T ? i2v : T - 1];
    float h0 = s1v - s0v, h1 = s2v - s1v;
    float h6_0 = h0 * (1.0f / 6.0f), h6_1 = h1 * (1.0f / 6.0f);

    // ---- batched reads from buf r ----
    float4 pva = *(const float4*)&PK[r][mhi][0];   // slots 0,1: (ka,kb,ka,kb)
    float4 pvb = *(const float4*)&PK[r][mhi][2];   // slots 2,3
    float4 pvc = *(const float4*)&PK[r][mhi][4];   // slots 4,5
    float4 pvd = *(const float4*)&PK[r][mhi][6];   // slots 6,7
    float4 gva = *(const float4*)&GK[r][0];        // gk slots 0-3
    float4 gvb = *(const float4*)&GK[r][4];        // gk slots 4-7
    // combines (same association as r15's rd4)
    float aC0 = fmaf(2.0f, pva.z, pva.x); aC0 = fmaf(2.0f, pvb.x, aC0); aC0 += pvb.z;
    float bC0 = fmaf(2.0f, pva.w, pva.y); bC0 = fmaf(2.0f, pvb.y, bC0); bC0 += pvb.w;
    float gC0 = fmaf(2.0f, gva.y, gva.x); gC0 = fmaf(2.0f, gva.z, gC0); gC0 += gva.w;
    float aC1 = fmaf(2.0f, pvc.z, pvc.x); aC1 = fmaf(2.0f, pvd.x, aC1); aC1 += pvd.z;
    float bC1 = fmaf(2.0f, pvc.w, pvc.y); bC1 = fmaf(2.0f, pvd.y, bC1); bC1 += pvd.w;
    float gC1 = fmaf(2.0f, gvb.y, gvb.x); gC1 = fmaf(2.0f, gvb.z, gC1); gC1 += gvb.w;
    // own-stage input history (scalar broadcast reads)
    const int sl = st ? st - 1 : 0;
    float2 pk0 = PK[r][mhi][sl];
    float2 pk1 = PK[r][mhi][4 + sl];
    float g0i = GK[r][sl], g1i = GK[r][4 + sl];
    float a0i = pk0.x, b0i = pk0.y, a1i = pk1.x, b1i = pk1.y;

    // ---- finalize exact y(2j-1), y(2j) (j>=1) ----
    if (j) {
      float yam = fmaf(h6p0, aC0, ya);
      float ybm = fmaf(h6p0, bC0, yb);
      ya = fmaf(h6p1, aC1, yam);
      yb = fmaf(h6p1, bC1, ybm);
      zb = fmaf(h6p1, gC1, fmaf(h6p0, gC0, fmaf(wins, hsumP, zb)));
      if (wv == 0 && (lane & 0x1E) == 0) {
        const size_t t0 = (size_t)(2 * j - 1);
        const int c = (lane >> 4) + (lane & 1);
        out[t0 * 4 + c] = (lane & 1) ? ybm : yam;
        out[(t0 + 1) * 4 + c] = (lane & 1) ? yb : ya;
      }
    }

    // ---- extrapolated same-step stage inputs ----
    float gin, kain, kbin;
    if (grp == 0) {
      gin = 2.0f * g1i - g0i;
      kain = 2.0f * a1i - a0i;
      kbin = 2.0f * b1i - b0i;
    } else {
      gin = 3.0f * g1i - 2.0f * g0i;
      kain = 3.0f * a1i - 2.0f * a0i;
      kbin = 3.0f * b1i - 2.0f * b0i;
    }

    // ---- y/zb for the eval ----
    float yA, yB, zB, hg;
    if (grp == 0) {
      yA = ya; yB = yb; zB = zb; hg = h0;
    } else {
      float cga = 2.0f * aC1 - aC0;
      float cgb = 2.0f * bC1 - bC0;
      float cgg = 2.0f * gC1 - gC0;
      yA = fmaf(h6_0, cga, ya);
      yB = fmaf(h6_0, cgb, yb);
      zB = fmaf(h6_0, cgg, fmaf(wins, h0, zb));
      hg = h1;
    }
    float cw = (st == 0) ? 0.0f : (st == 3) ? hg : 0.5f * hg;

    setpref(fmaf(cw, kain, yA), fmaf(cw, kbin, yB));
    STAGE(fmaf(cw, gin, zB));
    wrslot(w, pfa * na, pfb * nb);

    h6p0 = h6_0; h6p1 = h6_1; hsumP = h0 + h1;
    __syncthreads();
  }

  // ---- epilogue: y(T-1) from slots 0-3 of last-written buf ----
  if (T > 1) {
    const int rr = (NJ - 1) & 1;
    float4 pva = *(const float4*)&PK[rr][mhi][0];
    float4 pvb = *(const float4*)&PK[rr][mhi][2];
    float aE = fmaf(2.0f, pva.z, pva.x); aE = fmaf(2.0f, pvb.x, aE); aE += pvb.z;
    float bE = fmaf(2.0f, pva.w, pva.y); bE = fmaf(2.0f, pvb.y, bE); bE += pvb.w;
    float yaf = fmaf(h6p0, aE, ya);
    float ybf = fmaf(h6p0, bE, yb);
    if (wv == 0 && (lane & 0x1E) == 0)
      out[(size_t)(T - 1) * 4 + (lane >> 4) + (lane & 1)] =
          (lane & 1) ? ybf : yaf;
  }
}

extern "C" void kernel_launch(void* const* d_in, const int* in_sizes, int n_in,
                              void* d_out, int out_size, void* d_ws, size_t ws_size,
                              hipStream_t stream) {
  const float* s_grid = (const float*)d_in[0];
  const float* y0 = (const float*)d_in[1];
  const float* Win = (const float*)d_in[2];
  const float* bin_ = (const float*)d_in[3];
  const float* W1a = (const float*)d_in[4];
  const float* b1a = (const float*)d_in[5];
  const float* W1b = (const float*)d_in[6];
  const float* b1b = (const float*)d_in[7];
  const float* W2a = (const float*)d_in[8];
  const float* b2a = (const float*)d_in[9];
  const float* W2b = (const float*)d_in[10];
  const float* b2b = (const float*)d_in[11];
  const float* Wout = (const float*)d_in[12];
  const float* bout = (const float*)d_in[13];
  const float* A = (const float*)d_in[14];
  int T = in_sizes[0];

  ode_kernel<<<1, 512, 0, stream>>>(s_grid, y0, Win, bin_, W1a, b1a, W1b, b1b,
                                    W2a, b2a, W2b, b2b, Wout, bout, A,
                                    (float*)d_out, T);
}